// Round 2
// baseline (6539.391 us; speedup 1.0000x reference)
//
#include <hip/hip_runtime.h>
#include <hip/hip_bf16.h>
#include <cstdint>

typedef __attribute__((ext_vector_type(4))) float f32x4;
typedef __attribute__((ext_vector_type(8))) short s16x8;
typedef __hip_bfloat16 bf;

#define BDIM 256
#define MFMA16(a, b, c) __builtin_amdgcn_mfma_f32_16x16x32_bf16(a, b, c, 0, 0, 0)

__device__ __forceinline__ float eluf(float v) { return v > 0.f ? v : expm1f(v); }
__device__ __forceinline__ float sigmf_(float v) { return 1.f / (1.f + expf(-v)); }
__device__ __forceinline__ float softplusf_(float v) { return v > 20.f ? v : log1pf(expf(v)); }

// ---------------------------------------------------------------------------
// Generic bf16 MFMA gemm: out[M,N] = act( A[M,K] @ W[N,K]^T + bias + addC )
// A split into two K-concat segments (A1 K1 | A2 K2). W row-major [N,K].
// addC: optional bf16 [M,N] additive (precomputed partial products).
// D layout: col=lane&15, row=(lane>>4)*4+r (verified in R0/R1 pass).
// ---------------------------------------------------------------------------
struct GemmP {
    const bf* A1; const bf* A2; const bf* W;
    const float* bias; const bf* addC;
    float* outF; bf* outB;
};

template <int BM, int BN, int ACT, bool OUTB>
__global__ __launch_bounds__(BDIM) void gemm_k(GemmP p, int K1, int K2, int M, int N) {
    constexpr int LDT = 40;  // 80B LDS row stride: 2-way bank alias = free
    __shared__ short lA[BM * LDT];
    __shared__ short lW[BN * LDT];
    const int K = K1 + K2;
    const int bm = blockIdx.x * BM, bn = blockIdx.y * BN;
    const int tid = threadIdx.x, lane = tid & 63, wid = tid >> 6;
    constexpr int WM = BM / 2, WN = BN / 2;   // 2x2 wave grid
    constexpr int TM = WM / 16, TN = WN / 16;
    const int wm = (wid >> 1) * WM, wn = (wid & 1) * WN;
    const int q = lane >> 4, l16 = lane & 15;

    f32x4 acc[TM][TN] = {};

    for (int k0 = 0; k0 < K; k0 += 32) {
        for (int c = tid; c < BM * 4; c += BDIM) {
            int row = c >> 2, kc = c & 3, k = k0 + kc * 8;
            const bf* src = (k < K1) ? p.A1 + (size_t)(bm + row) * K1 + k
                                     : p.A2 + (size_t)(bm + row) * K2 + (k - K1);
            *(s16x8*)(lA + row * LDT + kc * 8) = *(const s16x8*)src;
        }
        for (int c = tid; c < BN * 4; c += BDIM) {
            int row = c >> 2, kc = c & 3, k = k0 + kc * 8;
            *(s16x8*)(lW + row * LDT + kc * 8) = *(const s16x8*)(p.W + (size_t)(bn + row) * K + k);
        }
        __syncthreads();
        s16x8 af[TM], wf[TN];
#pragma unroll
        for (int i = 0; i < TM; i++) af[i] = *(const s16x8*)(lA + (wm + i * 16 + l16) * LDT + q * 8);
#pragma unroll
        for (int j = 0; j < TN; j++) wf[j] = *(const s16x8*)(lW + (wn + j * 16 + l16) * LDT + q * 8);
#pragma unroll
        for (int i = 0; i < TM; i++)
#pragma unroll
            for (int j = 0; j < TN; j++) acc[i][j] = MFMA16(af[i], wf[j], acc[i][j]);
        __syncthreads();
    }

#pragma unroll
    for (int i = 0; i < TM; i++)
#pragma unroll
        for (int j = 0; j < TN; j++)
#pragma unroll
            for (int r = 0; r < 4; r++) {
                int row = bm + wm + i * 16 + q * 4 + r;
                int col = bn + wn + j * 16 + l16;
                float v = acc[i][j][r];
                if (p.bias) v += p.bias[col];
                if (p.addC) v += __bfloat162float(p.addC[(size_t)row * N + col]);
                if (ACT == 1) v = eluf(v);
                if (OUTB) p.outB[(size_t)row * N + col] = __float2bfloat16(v);
                else      p.outF[(size_t)row * N + col] = v;
            }
}

// ---------------------------------------------------------------------------
// Fused GRU kernel: per block computes 6 gate tiles (gi_r/z/n, gh_r/z/n) of
// [64 x 32] with K=1024, then the GRU pointwise in the epilogue.
// grid (4, 32). Per-block traffic ~640KB (per-CU BW floor ~4.5us).
// ---------------------------------------------------------------------------
__global__ __launch_bounds__(BDIM) void gru_fused(
    const bf* __restrict__ xb, const bf* __restrict__ hb_in,
    const bf* __restrict__ Wih, const bf* __restrict__ Whh,
    const float* __restrict__ bih, const float* __restrict__ bhh,
    const float* __restrict__ belief,
    float* __restrict__ h_out, bf* __restrict__ hb_out, bf* __restrict__ hs_slice) {
    constexpr int LDT = 40;
    __shared__ short lX[64 * LDT], lH[64 * LDT], lW[192 * LDT];
    const int bm = blockIdx.x * 64, bn = blockIdx.y * 32;
    const int tid = threadIdx.x, lane = tid & 63, wid = tid >> 6;
    const int wm = (wid >> 1) * 32, wn = (wid & 1) * 16;  // 2x2 waves over 64x32
    const int q = lane >> 4, l16 = lane & 15;

    f32x4 gi[3][2] = {}, gh[3][2] = {};

    for (int k0 = 0; k0 < 1024; k0 += 32) {
        for (int c = tid; c < 1280; c += BDIM) {
            int kc = c & 3, k = k0 + kc * 8;
            if (c < 256) {
                int row = c >> 2;
                *(s16x8*)(lX + row * LDT + kc * 8) = *(const s16x8*)(xb + (size_t)(bm + row) * 1024 + k);
            } else if (c < 512) {
                int row = (c >> 2) - 64;
                *(s16x8*)(lH + row * LDT + kc * 8) = *(const s16x8*)(hb_in + (size_t)(bm + row) * 1024 + k);
            } else {
                int wr = (c - 512) >> 2;  // [0,192): 6 gate tiles x 32 rows
                int g = wr >> 5, r32 = wr & 31;
                const bf* base = (g < 3) ? Wih + (size_t)(g * 1024 + bn + r32) * 1024
                                         : Whh + (size_t)((g - 3) * 1024 + bn + r32) * 1024;
                *(s16x8*)(lW + wr * LDT + kc * 8) = *(const s16x8*)(base + k);
            }
        }
        __syncthreads();
        s16x8 ax[2], ah[2], wf[6];
#pragma unroll
        for (int i = 0; i < 2; i++) {
            ax[i] = *(const s16x8*)(lX + (wm + i * 16 + l16) * LDT + q * 8);
            ah[i] = *(const s16x8*)(lH + (wm + i * 16 + l16) * LDT + q * 8);
        }
#pragma unroll
        for (int g = 0; g < 6; g++) wf[g] = *(const s16x8*)(lW + (g * 32 + wn + l16) * LDT + q * 8);
#pragma unroll
        for (int g = 0; g < 3; g++)
#pragma unroll
            for (int i = 0; i < 2; i++) {
                gi[g][i] = MFMA16(ax[i], wf[g], gi[g][i]);
                gh[g][i] = MFMA16(ah[i], wf[3 + g], gh[g][i]);
            }
        __syncthreads();
    }

    const int col = bn + wn + l16;
    const float bir = bih[col], biz = bih[1024 + col], bin = bih[2048 + col];
    const float bhr = bhh[col], bhz = bhh[1024 + col], bhn = bhh[2048 + col];
#pragma unroll
    for (int i = 0; i < 2; i++)
#pragma unroll
        for (int rr = 0; rr < 4; rr++) {
            int row = bm + wm + i * 16 + q * 4 + rr;
            size_t o = (size_t)row * 1024 + col;
            float r = sigmf_(gi[0][i][rr] + bir + gh[0][i][rr] + bhr);
            float z = sigmf_(gi[1][i][rr] + biz + gh[1][i][rr] + bhz);
            float n = tanhf(gi[2][i][rr] + bin + r * (gh[2][i][rr] + bhn));
            float h = (1.f - z) * n + z * belief[o];
            h_out[o] = h;
            bf hb = __float2bfloat16(h);
            hb_out[o] = hb;
            hs_slice[o] = hb;
        }
}

// ---------------------------------------------------------------------------
// Fused posterior head: msq tile (gathered cols j and j+128) gemm K=1024,
// then softplus/sample pointwise; writes post outputs + next-step s (bf16).
// grid (8, 4): block = 32 rows x (32 m-cols + 32 s-cols).
// ---------------------------------------------------------------------------
__global__ __launch_bounds__(BDIM) void pos_head(
    const bf* __restrict__ hq, const bf* __restrict__ Wpos,
    const float* __restrict__ bpos, const float* __restrict__ eps,
    float* __restrict__ o_st, float* __restrict__ o_mu, float* __restrict__ o_sd,
    const float* __restrict__ nt_next, bf* __restrict__ s_b) {
    constexpr int LDT = 40;
    __shared__ short lA[32 * LDT], lW[64 * LDT];
    __shared__ float lms[32][66];
    const int bm = blockIdx.x * 32, cg = blockIdx.y * 32;
    const int tid = threadIdx.x, lane = tid & 63, wid = tid >> 6;
    const int wm = (wid >> 1) * 16, wn = (wid & 1) * 32;
    const int q = lane >> 4, l16 = lane & 15;

    f32x4 acc[2] = {};
    for (int k0 = 0; k0 < 1024; k0 += 32) {
        for (int c = tid; c < 384; c += BDIM) {
            int kc = c & 3, k = k0 + kc * 8;
            if (c < 128) {
                int row = c >> 2;
                *(s16x8*)(lA + row * LDT + kc * 8) = *(const s16x8*)(hq + (size_t)(bm + row) * 1024 + k);
            } else {
                int wr = (c >> 2) - 32;  // [0,64): gathered W rows
                int n = (wr < 32) ? cg + wr : 96 + cg + wr;  // = 128 + cg + (wr-32)
                *(s16x8*)(lW + wr * LDT + kc * 8) = *(const s16x8*)(Wpos + (size_t)n * 1024 + k);
            }
        }
        __syncthreads();
        s16x8 a0 = *(const s16x8*)(lA + (wm + l16) * LDT + q * 8);
#pragma unroll
        for (int j = 0; j < 2; j++) {
            s16x8 wfj = *(const s16x8*)(lW + (wn + j * 16 + l16) * LDT + q * 8);
            acc[j] = MFMA16(a0, wfj, acc[j]);
        }
        __syncthreads();
    }
#pragma unroll
    for (int j = 0; j < 2; j++)
#pragma unroll
        for (int rr = 0; rr < 4; rr++) lms[wm + q * 4 + rr][wn + j * 16 + l16] = acc[j][rr];
    __syncthreads();

    for (int e = tid; e < 32 * 32; e += BDIM) {
        int row = e >> 5, jc = e & 31;
        int jj = cg + jc, b = bm + row;
        float m = lms[row][jc] + bpos[jj];
        float sraw = lms[row][32 + jc] + bpos[128 + jj];
        float s = softplusf_(sraw) + 0.1f;
        int gi_ = b * 128 + jj;
        float st = m + s * eps[gi_];
        o_mu[gi_] = m; o_sd[gi_] = s; o_st[gi_] = st;
        if (nt_next) s_b[gi_] = __float2bfloat16(st * nt_next[b]);
    }
}

// ---------------------------------------------------------------------------
// Prior head pointwise (batched over all T at the end).
// ---------------------------------------------------------------------------
__global__ __launch_bounds__(BDIM) void head_pw(const float* __restrict__ msq, const float* __restrict__ eps,
                                                float* __restrict__ o_st, float* __restrict__ o_mu,
                                                float* __restrict__ o_sd, int total) {
    int idx = blockIdx.x * BDIM + threadIdx.x;
    if (idx >= total) return;
    int b = idx >> 7, j = idx & 127;
    float m = msq[(size_t)b * 256 + j];
    float sraw = msq[(size_t)b * 256 + 128 + j];
    float s = softplusf_(sraw) + 0.1f;
    o_mu[idx] = m;
    o_sd[idx] = s;
    o_st[idx] = m + s * eps[idx];
}

// ---------------------------------------------------------------------------
// Init: s_b = bf16(prev_state * nt[0]), hb0 = bf16(prev_belief)
// ---------------------------------------------------------------------------
__global__ __launch_bounds__(BDIM) void init_k(const float* __restrict__ prev_state,
                                               const float* __restrict__ nt0,
                                               const float* __restrict__ prev_belief,
                                               bf* __restrict__ s_b, bf* __restrict__ bel_b) {
    int idx = blockIdx.x * BDIM + threadIdx.x;
    if (idx < 256 * 1024) bel_b[idx] = __float2bfloat16(prev_belief[idx]);
    if (idx < 256 * 128) {
        int b = idx >> 7;
        s_b[idx] = __float2bfloat16(prev_state[idx] * nt0[b]);
    }
}

// ---------------------------------------------------------------------------
// Strided-segment fp32 -> bf16 conversion (weight splits + activations).
// ---------------------------------------------------------------------------
struct CSeg { const float* src; bf* dst; int n4; int w4; int sstride; int soff; };
struct CArr { CSeg s[11]; };

__global__ __launch_bounds__(BDIM) void conv2_k(CArr ca) {
    int stride = gridDim.x * BDIM, g = blockIdx.x * BDIM + threadIdx.x;
    for (int a = 0; a < 11; a++) {
        CSeg cs = ca.s[a];
        for (int i = g; i < cs.n4; i += stride) {
            int row = i / cs.w4, cc = i - row * cs.w4;
            float4 v = *(const float4*)(cs.src + (size_t)row * cs.sstride + cs.soff + cc * 4);
            bf h0 = __float2bfloat16(v.x), h1 = __float2bfloat16(v.y);
            bf h2 = __float2bfloat16(v.z), h3 = __float2bfloat16(v.w);
            ushort4 o;
            o.x = *(unsigned short*)&h0; o.y = *(unsigned short*)&h1;
            o.z = *(unsigned short*)&h2; o.w = *(unsigned short*)&h3;
            *(ushort4*)((unsigned short*)cs.dst + (size_t)i * 4) = o;
        }
    }
}

// ---------------------------------------------------------------------------
extern "C" void kernel_launch(void* const* d_in, const int* in_sizes, int n_in,
                              void* d_out, int out_size, void* d_ws, size_t ws_size,
                              hipStream_t stream) {
    constexpr int B = 256, T = 50;
    constexpr size_t BB = (size_t)B * 1024;  // belief-slice elems
    constexpr size_t BS = (size_t)B * 128;   // state-slice elems

    const float* prev_state  = (const float*)d_in[0];
    const float* actions     = (const float*)d_in[1];
    const float* prev_belief = (const float*)d_in[2];
    const float* observ      = (const float*)d_in[3];
    const float* nonterm     = (const float*)d_in[4];
    const float* eps_p       = (const float*)d_in[5];
    const float* eps_q       = (const float*)d_in[6];
    const float* W_sa  = (const float*)d_in[7];
    const float* b_sa  = (const float*)d_in[8];
    const float* W_ih  = (const float*)d_in[9];
    const float* b_ih  = (const float*)d_in[10];
    const float* W_hh  = (const float*)d_in[11];
    const float* b_hh  = (const float*)d_in[12];
    const float* W_prh = (const float*)d_in[13];
    const float* b_prh = (const float*)d_in[14];
    const float* W_prs = (const float*)d_in[15];
    const float* b_prs = (const float*)d_in[16];
    const float* W_poh = (const float*)d_in[17];
    const float* b_poh = (const float*)d_in[18];
    const float* W_pos = (const float*)d_in[19];
    const float* b_pos = (const float*)d_in[20];
    float* out = (float*)d_out;
    (void)in_sizes; (void)n_in; (void)out_size; (void)ws_size;

    char* wsp = (char*)d_ws;
    size_t off = 0;
    auto alloc = [&](size_t bytes) -> void* {
        void* p = wsp + off;
        off = (off + bytes + 255) & ~(size_t)255;
        return p;
    };
    bf* Wih_b    = (bf*)alloc((size_t)3072 * 1024 * 2);
    bf* Whh_b    = (bf*)alloc((size_t)3072 * 1024 * 2);
    bf* Wprh_b   = (bf*)alloc((size_t)1024 * 1024 * 2);
    bf* Wprs_b   = (bf*)alloc((size_t)256 * 1024 * 2);
    bf* Wpos_b   = (bf*)alloc((size_t)256 * 1024 * 2);
    bf* Wpoh_h_b = (bf*)alloc((size_t)1024 * 1024 * 2);
    bf* Wpoh_o_b = (bf*)alloc((size_t)1024 * 1024 * 2);
    bf* Wsa_s_b  = (bf*)alloc((size_t)1024 * 128 * 2);
    bf* Wsa_a_b  = (bf*)alloc((size_t)1024 * 32 * 2);
    bf* act_b    = (bf*)alloc((size_t)T * B * 32 * 2);
    bf* obs_b    = (bf*)alloc((size_t)T * BB * 2);   // dead after preobs gemm
    bf* hp_b     = obs_b;                            // alias: prior hidden (end only)
    bf* preobs_b = (bf*)alloc((size_t)T * BB * 2);
    bf* prea_b   = (bf*)alloc((size_t)T * BB * 2);   // dead after last x-gemm
    float* mpsp  = (float*)prea_b;                   // alias: prior msq (end only)
    bf* hs_b     = (bf*)alloc((size_t)T * BB * 2);
    bf* s_b      = (bf*)alloc(BS * 2);
    bf* x_b      = (bf*)alloc(BB * 2);
    bf* hb0      = (bf*)alloc(BB * 2);
    bf* hb1      = (bf*)alloc(BB * 2);
    bf* hq_b     = (bf*)alloc(BB * 2);

    const size_t BEL = (size_t)T * BB;
    const size_t SML = (size_t)T * BS;
    float* o_bel  = out;
    float* o_prs  = out + BEL;
    float* o_prm  = o_prs + SML;
    float* o_prsd = o_prm + SML;
    float* o_pos  = o_prsd + SML;
    float* o_pom  = o_pos + SML;
    float* o_posd = o_pom + SML;

    // ---- one-time conversions + precomputations ----
    auto seg = [](const float* s, bf* d, int rows, int w, int sstride, int soff) {
        CSeg c; c.src = s; c.dst = d; c.n4 = rows * (w / 4); c.w4 = w / 4;
        c.sstride = sstride; c.soff = soff; return c;
    };
    CArr ca;
    ca.s[0]  = seg(W_ih,  Wih_b,    3072, 1024, 1024, 0);
    ca.s[1]  = seg(W_hh,  Whh_b,    3072, 1024, 1024, 0);
    ca.s[2]  = seg(W_prh, Wprh_b,   1024, 1024, 1024, 0);
    ca.s[3]  = seg(W_prs, Wprs_b,    256, 1024, 1024, 0);
    ca.s[4]  = seg(W_pos, Wpos_b,    256, 1024, 1024, 0);
    ca.s[5]  = seg(W_poh, Wpoh_h_b, 1024, 1024, 2048, 0);
    ca.s[6]  = seg(W_poh, Wpoh_o_b, 1024, 1024, 2048, 1024);
    ca.s[7]  = seg(W_sa,  Wsa_s_b,  1024,  128,  160, 0);
    ca.s[8]  = seg(W_sa,  Wsa_a_b,  1024,   32,  160, 128);
    ca.s[9]  = seg(actions, act_b, 12800,   32,   32, 0);
    ca.s[10] = seg(observ,  obs_b, 12800, 1024, 1024, 0);
    conv2_k<<<2048, BDIM, 0, stream>>>(ca);
    init_k<<<1024, BDIM, 0, stream>>>(prev_state, nonterm, prev_belief, s_b, hb0);

    {   // prea = actions @ Wsa_a^T + b_sa   [12800,1024], K=32
        GemmP p{act_b, nullptr, Wsa_a_b, b_sa, nullptr, nullptr, prea_b};
        gemm_k<128, 64, 0, true><<<dim3(100, 16), BDIM, 0, stream>>>(p, 32, 0, 12800, 1024);
    }
    {   // preobs = obs @ Wpoh_o^T + b_poh   [12800,1024], K=1024
        GemmP p{obs_b, nullptr, Wpoh_o_b, b_poh, nullptr, nullptr, preobs_b};
        gemm_k<128, 64, 0, true><<<dim3(100, 16), BDIM, 0, stream>>>(p, 1024, 0, 12800, 1024);
    }
    {   // x_0 = elu(s_0 @ Wsa_s^T + prea_0)   [256,1024], K=128
        GemmP p{s_b, nullptr, Wsa_s_b, nullptr, prea_b, nullptr, x_b};
        gemm_k<64, 64, 1, true><<<dim3(4, 16), BDIM, 0, stream>>>(p, 128, 0, 256, 1024);
    }

    // ---- sequential scan: 4 launches/step (A,B,C,D) ----
    for (int t = 0; t < T; t++) {
        bf* hin  = (t & 1) ? hb1 : hb0;
        bf* hout = (t & 1) ? hb0 : hb1;
        const float* belf = (t == 0) ? prev_belief : (o_bel + (size_t)(t - 1) * BB);
        // A: GRU (gi+gh gemms + pointwise) -> h
        gru_fused<<<dim3(4, 32), BDIM, 0, stream>>>(
            x_b, hin, Wih_b, Whh_b, b_ih, b_hh, belf,
            o_bel + (size_t)t * BB, hout, hs_b + (size_t)t * BB);
        // B: hq = elu(h @ Wpoh_h^T + preobs_t)   [256,1024], K=1024
        {
            GemmP p{hout, nullptr, Wpoh_h_b, nullptr, preobs_b + (size_t)t * BB, nullptr, hq_b};
            gemm_k<64, 32, 1, true><<<dim3(4, 32), BDIM, 0, stream>>>(p, 1024, 0, 256, 1024);
        }
        // C: posterior head (pos gemm + softplus/sample) -> outputs + s_{t+1}
        pos_head<<<dim3(8, 4), BDIM, 0, stream>>>(
            hq_b, Wpos_b, b_pos, eps_q + (size_t)t * BS,
            o_pos + (size_t)t * BS, o_pom + (size_t)t * BS, o_posd + (size_t)t * BS,
            (t + 1 < T) ? nonterm + (size_t)(t + 1) * B : nullptr, s_b);
        // D: x_{t+1} = elu(s_{t+1} @ Wsa_s^T + prea_{t+1})   K=128
        if (t + 1 < T) {
            GemmP p{s_b, nullptr, Wsa_s_b, nullptr, prea_b + (size_t)(t + 1) * BB, nullptr, x_b};
            gemm_k<64, 64, 1, true><<<dim3(4, 16), BDIM, 0, stream>>>(p, 128, 0, 256, 1024);
        }
    }

    // ---- prior head, batched over all T ----
    {   // hp = elu(hs @ Wprh^T + b_prh)   [12800,1024]
        GemmP p{hs_b, nullptr, Wprh_b, b_prh, nullptr, nullptr, hp_b};
        gemm_k<128, 64, 1, true><<<dim3(100, 16), BDIM, 0, stream>>>(p, 1024, 0, 12800, 1024);
    }
    {   // mpsp = hp @ Wprs^T + b_prs   [12800,256]
        GemmP p{hp_b, nullptr, Wprs_b, b_prs, nullptr, mpsp, nullptr};
        gemm_k<128, 64, 0, false><<<dim3(100, 4), BDIM, 0, stream>>>(p, 1024, 0, 12800, 256);
    }
    head_pw<<<(T * B * 128) / BDIM, BDIM, 0, stream>>>(mpsp, eps_p, o_prs, o_prm, o_prsd, T * B * 128);
}

// Round 3
// 6373.302 us; speedup vs baseline: 1.0261x; 1.0261x over previous
//
#include <hip/hip_runtime.h>
#include <hip/hip_bf16.h>
#include <cstdint>

typedef __attribute__((ext_vector_type(4))) float f32x4;
typedef __attribute__((ext_vector_type(8))) short s16x8;
typedef __hip_bfloat16 bf;

#define BDIM 256
#define MFMA16(a, b, c) __builtin_amdgcn_mfma_f32_16x16x32_bf16(a, b, c, 0, 0, 0)

__device__ __forceinline__ float eluf(float v) { return v > 0.f ? v : expm1f(v); }
__device__ __forceinline__ float sigmf_(float v) { return 1.f / (1.f + expf(-v)); }
__device__ __forceinline__ float softplusf_(float v) { return v > 20.f ? v : log1pf(expf(v)); }

// raw barrier / waitcnt (keep global_load_lds prefetches in flight across s_barrier;
// __syncthreads would drain vmcnt(0) and kill the ring)
template <int N> __device__ __forceinline__ void wait_vm() {
    asm volatile("s_waitcnt vmcnt(%0)" ::"n"(N) : "memory");
}
__device__ __forceinline__ void lbar() { asm volatile("s_barrier" ::: "memory"); }

__device__ __forceinline__ void gload16(const void* g, void* l) {
    __builtin_amdgcn_global_load_lds((const __attribute__((address_space(1))) void*)g,
                                     (__attribute__((address_space(3))) void*)l, 16, 0, 0);
}

// ---------------------------------------------------------------------------
// Persistent-stage tiled gemm engine.
// Block tile: [64 rows x 16 cols x NGW weight-tiles], K streamed in 64-elem
// slots through a 3-deep LDS ring filled by global_load_lds (16B chunks).
// LDS slot: A[64 rows][8 chunks] then W[NWpad rows][8 chunks]; chunk position
// p holds global k-chunk p^(row&7) (XOR swizzle -> conflict-free ds_read_b128).
// Stages: 0=G (gates, two-segment A=x|h, W=Wih|Whh, 4 accs: r,z,gi_n,gh_n)
//         1=Q (hq)   2=S (posterior msq, 2 gathered col groups)   3=X (next x)
// ---------------------------------------------------------------------------
template <int STG, int NSLOT>
__device__ __forceinline__ void gemm_stage(
    char* lds, int w, int lane, int m, int c,
    const bf* __restrict__ A1, const bf* __restrict__ A2, int astride,
    const bf* __restrict__ W1, const bf* __restrict__ W2, int wstride,
    f32x4* acc) {
    constexpr int NI = (STG == 0) ? 4 : 3;         // global_load_lds instrs / wave / slot
    constexpr int SLOTB = (STG == 0) ? 16384 : 12288;
    constexpr int NGW = (STG == 0) ? 3 : ((STG == 2) ? 2 : 1);
    const int l16 = lane & 15, q = lane >> 4;

    // per-chunk global bases (k-offset advances per slot; swizzled kc folded in)
    const bf* gA[NI];
    const bf* gB[NI];
    int lo[NI];
#pragma unroll
    for (int i = 0; i < NI; i++) {
        int ch = (w * NI + i) * 64 + lane;
        int p = ch & 7;
        lo[i] = (w * NI + i) * 1024;
        if (ch < 512) {  // A chunk
            int r = ch >> 3;
            int kc = p ^ (r & 7);
            gA[i] = A1 + (size_t)(m * 64 + r) * astride + kc * 8;
            gB[i] = A2 + (size_t)(m * 64 + r) * astride + kc * 8;
        } else {  // W chunk (gathered rows)
            int wr = (ch - 512) >> 3;
            int kc = p ^ (wr & 7);
            int row;
            if (STG == 0) { int wrr = (wr < 48) ? wr : wr - 48; row = (wrr >> 4) * 1024 + c * 16 + (wrr & 15); }
            else if (STG == 2) { row = (wr < 16) ? (c * 16 + wr) : (128 + c * 16 + (wr - 16)); }
            else { row = c * 16 + (wr & 15); }
            gA[i] = W1 + (size_t)row * wstride + kc * 8;
            gB[i] = W2 + (size_t)row * wstride + kc * 8;
        }
    }
    auto issue = [&](int s) {
        int k0 = s * 64;
        char* lb = lds + (s % 3) * SLOTB;
#pragma unroll
        for (int i = 0; i < NI; i++) {
            const bf* g = (k0 < 1024) ? (gA[i] + k0) : (gB[i] + (k0 - 1024));
            gload16((const void*)g, (void*)(lb + lo[i]));
        }
    };
    issue(0);
    if (NSLOT > 1) issue(1);
    for (int s = 0; s < NSLOT; s++) {
        if (s + 2 < NSLOT) issue(s + 2);
        int newer = ((NSLOT - 1 - s) < 2) ? (NSLOT - 1 - s) : 2;
        if (newer >= 2) wait_vm<2 * NI>();
        else if (newer == 1) wait_vm<NI>();
        else wait_vm<0>();
        lbar();  // slot s landed for all waves
        {
            char* lb = lds + (s % 3) * SLOTB;
            const int arow = w * 16 + l16;
            s16x8 af[2];
#pragma unroll
            for (int sub = 0; sub < 2; sub++) {
                int kc = sub * 4 + q, p = kc ^ (arow & 7);
                af[sub] = *(const s16x8*)(lb + (arow * 8 + p) * 16);
            }
            const bool second = (s * 64 >= 1024);  // G: h/Whh half (gh_n split)
#pragma unroll
            for (int g = 0; g < NGW; g++) {
                int wrow = g * 16 + l16;
#pragma unroll
                for (int sub = 0; sub < 2; sub++) {
                    int kc = sub * 4 + q, p = kc ^ (wrow & 7);
                    s16x8 wf = *(const s16x8*)(lb + 8192 + (wrow * 8 + p) * 16);
                    if (STG == 0 && g == 2) {
                        if (second) acc[3] = MFMA16(af[sub], wf, acc[3]);
                        else        acc[2] = MFMA16(af[sub], wf, acc[2]);
                    } else {
                        acc[g] = MFMA16(af[sub], wf, acc[g]);
                    }
                }
            }
        }
        lbar();  // all waves done reading slot s (its memory is reused next iter)
    }
}

// ---------------------------------------------------------------------------
// Device-scope grid barrier (monotone counter; blocks all resident: grid=256
// blocks of 256 thr, <=48KB LDS -> 1 block/CU on 256 CUs).
// ---------------------------------------------------------------------------
__device__ __forceinline__ void grid_barrier(unsigned* bar, unsigned target) {
    __syncthreads();
    if (threadIdx.x == 0) {
        __threadfence();  // release: writeback local XCD L2
        __hip_atomic_fetch_add(bar, 1u, __ATOMIC_RELEASE, __HIP_MEMORY_SCOPE_AGENT);
        while (__hip_atomic_load(bar, __ATOMIC_RELAXED, __HIP_MEMORY_SCOPE_AGENT) < target)
            __builtin_amdgcn_s_sleep(2);
        __threadfence();  // acquire: invalidate local L2
    }
    __syncthreads();
}

struct PArgs {
    const bf *Wih, *Whh, *Wpoh_h, *Wpos, *Wsa_s;
    const bf *prea, *preobs;
    const float *b_ih, *b_hh, *b_pos;
    const float *prev_belief, *nonterm, *eps_q;
    float *o_bel, *o_pos, *o_pom, *o_posd;
    bf *x_b, *hb0, *hb1, *hq_b, *s_b, *hs_b;
    unsigned* bar;
};

__global__ __launch_bounds__(256, 1) void rssm_persist(PArgs a) {
    __shared__ char lds[49152];
    const int tid = threadIdx.x, bid = blockIdx.x;
    const int w = tid >> 6, lane = tid & 63, l16 = lane & 15, q = lane >> 4;
    const int m = bid & 3, c = bid >> 2;  // 4 m-groups x 64 col-groups
    unsigned bcnt = 0;

    // ---- X(-1): x_0 = elu(s_0 @ Wsa_s^T + prea_0) ----
    {
        f32x4 acc[1] = {};
        gemm_stage<3, 2>(lds, w, lane, m, c, a.s_b, a.s_b, 128, a.Wsa_s, a.Wsa_s, 128, acc);
        int col = c * 16 + l16;
#pragma unroll
        for (int rr = 0; rr < 4; rr++) {
            int row = m * 64 + w * 16 + q * 4 + rr;
            size_t o = (size_t)row * 1024 + col;
            a.x_b[o] = __float2bfloat16(eluf(acc[0][rr] + __bfloat162float(a.prea[o])));
        }
    }
    grid_barrier(a.bar, (++bcnt) * 256);

    for (int t = 0; t < 50; t++) {
        const bf* hprev = (t & 1) ? a.hb1 : a.hb0;
        bf* hcur = (t & 1) ? a.hb0 : a.hb1;
        const float* belprev = t ? (a.o_bel + (size_t)(t - 1) * 262144) : a.prev_belief;

        // ---- G: gates gemm (K=2048 over [x|h]) + GRU pointwise ----
        {
            f32x4 acc[4] = {};  // r, z, gi_n (x half), gh_n (h half)
            gemm_stage<0, 32>(lds, w, lane, m, c, a.x_b, hprev, 1024, a.Wih, a.Whh, 1024, acc);
            int col = c * 16 + l16;
            float bir = a.b_ih[col] + a.b_hh[col];
            float biz = a.b_ih[1024 + col] + a.b_hh[1024 + col];
            float bin = a.b_ih[2048 + col], bhn = a.b_hh[2048 + col];
            float* obel = a.o_bel + (size_t)t * 262144;
            bf* hs = a.hs_b + (size_t)t * 262144;
#pragma unroll
            for (int rr = 0; rr < 4; rr++) {
                int row = m * 64 + w * 16 + q * 4 + rr;
                size_t o = (size_t)row * 1024 + col;
                float r = sigmf_(acc[0][rr] + bir);
                float z = sigmf_(acc[1][rr] + biz);
                float n = tanhf(acc[2][rr] + bin + r * (acc[3][rr] + bhn));
                float h = (1.f - z) * n + z * belprev[o];
                obel[o] = h;
                bf hb = __float2bfloat16(h);
                hcur[o] = hb;
                hs[o] = hb;
            }
        }
        grid_barrier(a.bar, (++bcnt) * 256);

        // ---- Q: hq = elu(h @ Wpoh_h^T + preobs_t) ----
        {
            f32x4 acc[1] = {};
            gemm_stage<1, 16>(lds, w, lane, m, c, hcur, hcur, 1024, a.Wpoh_h, a.Wpoh_h, 1024, acc);
            const bf* pre = a.preobs + (size_t)t * 262144;
            int col = c * 16 + l16;
#pragma unroll
            for (int rr = 0; rr < 4; rr++) {
                int row = m * 64 + w * 16 + q * 4 + rr;
                size_t o = (size_t)row * 1024 + col;
                a.hq_b[o] = __float2bfloat16(eluf(acc[0][rr] + __bfloat162float(pre[o])));
            }
        }
        grid_barrier(a.bar, (++bcnt) * 256);

        // ---- S: posterior msq + sample (+ s_{t+1}); 32 busy blocks ----
        if (c < 8) {
            f32x4 acc[2] = {};
            gemm_stage<2, 16>(lds, w, lane, m, c, a.hq_b, a.hq_b, 1024, a.Wpos, a.Wpos, 1024, acc);
            int j = c * 16 + l16;
            const float* eps = a.eps_q + (size_t)t * 32768;
            float* om = a.o_pom + (size_t)t * 32768;
            float* osd = a.o_posd + (size_t)t * 32768;
            float* ost = a.o_pos + (size_t)t * 32768;
#pragma unroll
            for (int rr = 0; rr < 4; rr++) {
                int row = m * 64 + w * 16 + q * 4 + rr;
                int o = row * 128 + j;
                float mm = acc[0][rr] + a.b_pos[j];
                float ss = softplusf_(acc[1][rr] + a.b_pos[128 + j]) + 0.1f;
                float st = mm + ss * eps[o];
                om[o] = mm; osd[o] = ss; ost[o] = st;
                if (t + 1 < 50) a.s_b[o] = __float2bfloat16(st * a.nonterm[(t + 1) * 256 + row]);
            }
        }
        grid_barrier(a.bar, (++bcnt) * 256);

        // ---- X: x_{t+1} = elu(s @ Wsa_s^T + prea_{t+1}) ----
        if (t + 1 < 50) {
            f32x4 acc[1] = {};
            gemm_stage<3, 2>(lds, w, lane, m, c, a.s_b, a.s_b, 128, a.Wsa_s, a.Wsa_s, 128, acc);
            const bf* prea = a.prea + (size_t)(t + 1) * 262144;
            int col = c * 16 + l16;
#pragma unroll
            for (int rr = 0; rr < 4; rr++) {
                int row = m * 64 + w * 16 + q * 4 + rr;
                size_t o = (size_t)row * 1024 + col;
                a.x_b[o] = __float2bfloat16(eluf(acc[0][rr] + __bfloat162float(prea[o])));
            }
            grid_barrier(a.bar, (++bcnt) * 256);
        }
    }
}

// ---------------------------------------------------------------------------
// Bulk gemm for prolog/epilog (R2 code, unchanged).
// ---------------------------------------------------------------------------
struct GemmP {
    const bf* A1; const bf* A2; const bf* W;
    const float* bias; const bf* addC;
    float* outF; bf* outB;
};

template <int BM, int BN, int ACT, bool OUTB>
__global__ __launch_bounds__(BDIM) void gemm_k(GemmP p, int K1, int K2, int M, int N) {
    constexpr int LDT = 40;
    __shared__ short lA[BM * LDT];
    __shared__ short lW[BN * LDT];
    const int K = K1 + K2;
    const int bm = blockIdx.x * BM, bn = blockIdx.y * BN;
    const int tid = threadIdx.x, lane = tid & 63, wid = tid >> 6;
    constexpr int WM = BM / 2, WN = BN / 2;
    constexpr int TM = WM / 16, TN = WN / 16;
    const int wm = (wid >> 1) * WM, wn = (wid & 1) * WN;
    const int q = lane >> 4, l16 = lane & 15;

    f32x4 acc[TM][TN] = {};
    for (int k0 = 0; k0 < K; k0 += 32) {
        for (int cc = tid; cc < BM * 4; cc += BDIM) {
            int row = cc >> 2, kc = cc & 3, k = k0 + kc * 8;
            const bf* src = (k < K1) ? p.A1 + (size_t)(bm + row) * K1 + k
                                     : p.A2 + (size_t)(bm + row) * K2 + (k - K1);
            *(s16x8*)(lA + row * LDT + kc * 8) = *(const s16x8*)src;
        }
        for (int cc = tid; cc < BN * 4; cc += BDIM) {
            int row = cc >> 2, kc = cc & 3, k = k0 + kc * 8;
            *(s16x8*)(lW + row * LDT + kc * 8) = *(const s16x8*)(p.W + (size_t)(bn + row) * K + k);
        }
        __syncthreads();
        s16x8 af[TM], wf[TN];
#pragma unroll
        for (int i = 0; i < TM; i++) af[i] = *(const s16x8*)(lA + (wm + i * 16 + l16) * LDT + q * 8);
#pragma unroll
        for (int j = 0; j < TN; j++) wf[j] = *(const s16x8*)(lW + (wn + j * 16 + l16) * LDT + q * 8);
#pragma unroll
        for (int i = 0; i < TM; i++)
#pragma unroll
            for (int j = 0; j < TN; j++) acc[i][j] = MFMA16(af[i], wf[j], acc[i][j]);
        __syncthreads();
    }
#pragma unroll
    for (int i = 0; i < TM; i++)
#pragma unroll
        for (int j = 0; j < TN; j++)
#pragma unroll
            for (int r = 0; r < 4; r++) {
                int row = bm + wm + i * 16 + q * 4 + r;
                int col = bn + wn + j * 16 + l16;
                float v = acc[i][j][r];
                if (p.bias) v += p.bias[col];
                if (p.addC) v += __bfloat162float(p.addC[(size_t)row * N + col]);
                if (ACT == 1) v = eluf(v);
                if (OUTB) p.outB[(size_t)row * N + col] = __float2bfloat16(v);
                else      p.outF[(size_t)row * N + col] = v;
            }
}

__global__ __launch_bounds__(BDIM) void head_pw(const float* __restrict__ msq, const float* __restrict__ eps,
                                                float* __restrict__ o_st, float* __restrict__ o_mu,
                                                float* __restrict__ o_sd, int total) {
    int idx = blockIdx.x * BDIM + threadIdx.x;
    if (idx >= total) return;
    int b = idx >> 7, j = idx & 127;
    float m = msq[(size_t)b * 256 + j];
    float s = softplusf_(msq[(size_t)b * 256 + 128 + j]) + 0.1f;
    o_mu[idx] = m;
    o_sd[idx] = s;
    o_st[idx] = m + s * eps[idx];
}

__global__ __launch_bounds__(BDIM) void init_k(const float* __restrict__ prev_state,
                                               const float* __restrict__ nt0,
                                               const float* __restrict__ prev_belief,
                                               bf* __restrict__ s_b, bf* __restrict__ bel_b) {
    int idx = blockIdx.x * BDIM + threadIdx.x;
    if (idx < 256 * 1024) bel_b[idx] = __float2bfloat16(prev_belief[idx]);
    if (idx < 256 * 128) {
        int b = idx >> 7;
        s_b[idx] = __float2bfloat16(prev_state[idx] * nt0[b]);
    }
}

struct CSeg { const float* src; bf* dst; int n4; int w4; int sstride; int soff; };
struct CArr { CSeg s[11]; };

__global__ __launch_bounds__(BDIM) void conv2_k(CArr ca) {
    int stride = gridDim.x * BDIM, g = blockIdx.x * BDIM + threadIdx.x;
    for (int a = 0; a < 11; a++) {
        CSeg cs = ca.s[a];
        for (int i = g; i < cs.n4; i += stride) {
            int row = i / cs.w4, cc = i - row * cs.w4;
            float4 v = *(const float4*)(cs.src + (size_t)row * cs.sstride + cs.soff + cc * 4);
            bf h0 = __float2bfloat16(v.x), h1 = __float2bfloat16(v.y);
            bf h2 = __float2bfloat16(v.z), h3 = __float2bfloat16(v.w);
            ushort4 o;
            o.x = *(unsigned short*)&h0; o.y = *(unsigned short*)&h1;
            o.z = *(unsigned short*)&h2; o.w = *(unsigned short*)&h3;
            *(ushort4*)((unsigned short*)cs.dst + (size_t)i * 4) = o;
        }
    }
}

// ---------------------------------------------------------------------------
extern "C" void kernel_launch(void* const* d_in, const int* in_sizes, int n_in,
                              void* d_out, int out_size, void* d_ws, size_t ws_size,
                              hipStream_t stream) {
    constexpr int B = 256, T = 50;
    constexpr size_t BB = (size_t)B * 1024;
    constexpr size_t BS = (size_t)B * 128;

    const float* prev_state  = (const float*)d_in[0];
    const float* actions     = (const float*)d_in[1];
    const float* prev_belief = (const float*)d_in[2];
    const float* observ      = (const float*)d_in[3];
    const float* nonterm     = (const float*)d_in[4];
    const float* eps_p       = (const float*)d_in[5];
    const float* eps_q       = (const float*)d_in[6];
    const float* W_sa  = (const float*)d_in[7];
    const float* b_sa  = (const float*)d_in[8];
    const float* W_ih  = (const float*)d_in[9];
    const float* b_ih  = (const float*)d_in[10];
    const float* W_hh  = (const float*)d_in[11];
    const float* b_hh  = (const float*)d_in[12];
    const float* W_prh = (const float*)d_in[13];
    const float* b_prh = (const float*)d_in[14];
    const float* W_prs = (const float*)d_in[15];
    const float* b_prs = (const float*)d_in[16];
    const float* W_poh = (const float*)d_in[17];
    const float* b_poh = (const float*)d_in[18];
    const float* W_pos = (const float*)d_in[19];
    const float* b_pos = (const float*)d_in[20];
    float* out = (float*)d_out;
    (void)in_sizes; (void)n_in; (void)out_size; (void)ws_size;

    char* wsp = (char*)d_ws;
    size_t off = 0;
    auto alloc = [&](size_t bytes) -> void* {
        void* p = wsp + off;
        off = (off + bytes + 255) & ~(size_t)255;
        return p;
    };
    bf* Wih_b    = (bf*)alloc((size_t)3072 * 1024 * 2);
    bf* Whh_b    = (bf*)alloc((size_t)3072 * 1024 * 2);
    bf* Wprh_b   = (bf*)alloc((size_t)1024 * 1024 * 2);
    bf* Wprs_b   = (bf*)alloc((size_t)256 * 1024 * 2);
    bf* Wpos_b   = (bf*)alloc((size_t)256 * 1024 * 2);
    bf* Wpoh_h_b = (bf*)alloc((size_t)1024 * 1024 * 2);
    bf* Wpoh_o_b = (bf*)alloc((size_t)1024 * 1024 * 2);
    bf* Wsa_s_b  = (bf*)alloc((size_t)1024 * 128 * 2);
    bf* Wsa_a_b  = (bf*)alloc((size_t)1024 * 32 * 2);
    bf* act_b    = (bf*)alloc((size_t)T * B * 32 * 2);
    bf* obs_b    = (bf*)alloc((size_t)T * BB * 2);   // dead after preobs gemm
    bf* hp_b     = obs_b;                            // alias: prior hidden (epilog)
    bf* preobs_b = (bf*)alloc((size_t)T * BB * 2);
    bf* prea_b   = (bf*)alloc((size_t)T * BB * 2);   // dead after persistent kernel
    float* mpsp  = (float*)prea_b;                   // alias: prior msq (epilog)
    bf* hs_b     = (bf*)alloc((size_t)T * BB * 2);
    bf* s_b      = (bf*)alloc(BS * 2);
    bf* x_b      = (bf*)alloc(BB * 2);
    bf* hb0      = (bf*)alloc(BB * 2);
    bf* hb1      = (bf*)alloc(BB * 2);
    bf* hq_b     = (bf*)alloc(BB * 2);
    unsigned* bar = (unsigned*)alloc(256);

    const size_t BEL = (size_t)T * BB;
    const size_t SML = (size_t)T * BS;
    float* o_bel  = out;
    float* o_prs  = out + BEL;
    float* o_prm  = o_prs + SML;
    float* o_prsd = o_prm + SML;
    float* o_pos  = o_prsd + SML;
    float* o_pom  = o_pos + SML;
    float* o_posd = o_pom + SML;

    // ---- prolog: conversions, init, hoisted gemms ----
    auto seg = [](const float* s, bf* d, int rows, int w, int sstride, int soff) {
        CSeg c; c.src = s; c.dst = d; c.n4 = rows * (w / 4); c.w4 = w / 4;
        c.sstride = sstride; c.soff = soff; return c;
    };
    CArr ca;
    ca.s[0]  = seg(W_ih,  Wih_b,    3072, 1024, 1024, 0);
    ca.s[1]  = seg(W_hh,  Whh_b,    3072, 1024, 1024, 0);
    ca.s[2]  = seg(W_prh, Wprh_b,   1024, 1024, 1024, 0);
    ca.s[3]  = seg(W_prs, Wprs_b,    256, 1024, 1024, 0);
    ca.s[4]  = seg(W_pos, Wpos_b,    256, 1024, 1024, 0);
    ca.s[5]  = seg(W_poh, Wpoh_h_b, 1024, 1024, 2048, 0);
    ca.s[6]  = seg(W_poh, Wpoh_o_b, 1024, 1024, 2048, 1024);
    ca.s[7]  = seg(W_sa,  Wsa_s_b,  1024,  128,  160, 0);
    ca.s[8]  = seg(W_sa,  Wsa_a_b,  1024,   32,  160, 128);
    ca.s[9]  = seg(actions, act_b, 12800,   32,   32, 0);
    ca.s[10] = seg(observ,  obs_b, 12800, 1024, 1024, 0);
    conv2_k<<<2048, BDIM, 0, stream>>>(ca);
    init_k<<<1024, BDIM, 0, stream>>>(prev_state, nonterm, prev_belief, s_b, hb0);
    {   // prea = actions @ Wsa_a^T + b_sa
        GemmP p{act_b, nullptr, Wsa_a_b, b_sa, nullptr, nullptr, prea_b};
        gemm_k<128, 64, 0, true><<<dim3(100, 16), BDIM, 0, stream>>>(p, 32, 0, 12800, 1024);
    }
    {   // preobs = obs @ Wpoh_o^T + b_poh
        GemmP p{obs_b, nullptr, Wpoh_o_b, b_poh, nullptr, nullptr, preobs_b};
        gemm_k<128, 64, 0, true><<<dim3(100, 16), BDIM, 0, stream>>>(p, 1024, 0, 12800, 1024);
    }

    // ---- the whole scan: one persistent kernel ----
    hipMemsetAsync(bar, 0, 64, stream);
    PArgs pa;
    pa.Wih = Wih_b; pa.Whh = Whh_b; pa.Wpoh_h = Wpoh_h_b; pa.Wpos = Wpos_b; pa.Wsa_s = Wsa_s_b;
    pa.prea = prea_b; pa.preobs = preobs_b;
    pa.b_ih = b_ih; pa.b_hh = b_hh; pa.b_pos = b_pos;
    pa.prev_belief = prev_belief; pa.nonterm = nonterm; pa.eps_q = eps_q;
    pa.o_bel = o_bel; pa.o_pos = o_pos; pa.o_pom = o_pom; pa.o_posd = o_posd;
    pa.x_b = x_b; pa.hb0 = hb0; pa.hb1 = hb1; pa.hq_b = hq_b; pa.s_b = s_b; pa.hs_b = hs_b;
    pa.bar = bar;
    rssm_persist<<<256, 256, 0, stream>>>(pa);

    // ---- epilog: prior head batched over all T ----
    {
        GemmP p{hs_b, nullptr, Wprh_b, b_prh, nullptr, nullptr, hp_b};
        gemm_k<128, 64, 1, true><<<dim3(100, 16), BDIM, 0, stream>>>(p, 1024, 0, 12800, 1024);
    }
    {
        GemmP p{hp_b, nullptr, Wprs_b, b_prs, nullptr, mpsp, nullptr};
        gemm_k<128, 64, 0, false><<<dim3(100, 4), BDIM, 0, stream>>>(p, 1024, 0, 12800, 256);
    }
    head_pw<<<(T * B * 128) / BDIM, BDIM, 0, stream>>>(mpsp, eps_p, o_prs, o_prm, o_prsd, T * B * 128);
}